// Round 1
// baseline (617.986 us; speedup 1.0000x reference)
//
#include <hip/hip_runtime.h>
#include <hip/hip_bf16.h>
#include <cstdint>

// Problem constants
// B=128, P=168, M=8, HIDC=50, HIDR=50, HIDS=5, CK=6, SKIP=24, HW=24
// O = P*HIDC*CK = 50400, Kdim = P*M = 1344, L = 163, PT = 6

typedef __attribute__((ext_vector_type(8))) short short8;   // 8 bf16 (4 VGPRs)
typedef __attribute__((ext_vector_type(4))) float f32x4;    // MFMA acc

__device__ __forceinline__ unsigned short bf16rn(float f) {
    unsigned u = __float_as_uint(f);
    return (unsigned short)((u + 0x7FFFu + ((u >> 16) & 1u)) >> 16);
}
__device__ __forceinline__ unsigned pk2(float a, float b) {
    return ((unsigned)bf16rn(b) << 16) | (unsigned)bf16rn(a);
}
__device__ __forceinline__ uint4 pack8(float4 f0, float4 f1) {
    uint4 u;
    u.x = pk2(f0.x, f0.y); u.y = pk2(f0.z, f0.w);
    u.z = pk2(f1.x, f1.y); u.w = pk2(f1.z, f1.w);
    return u;
}
__device__ __forceinline__ float bf2f(unsigned short u) {
    return __uint_as_float((unsigned)u << 16);
}
__device__ __forceinline__ float sigmf(float x) { return 1.f / (1.f + __expf(-x)); }
__device__ __forceinline__ float tanhf_(float x) { return 1.f - 2.f / (__expf(2.f * x) + 1.f); }

// ---------------------------------------------------------------------------
// K1: c[b][o] = relu(xf @ wf^T + conv_b), stored bf16.  M=128, N=50400, K=1344.
// Tile 128x112, BK=64. fp32 global loads -> bf16 convert in regs -> LDS packets.
// LDS layout: [kslot][row] packets of 8 bf16 (16B), row dim padded (+1) so both
// staging writes and frag reads are perfectly bank-distributed.
// ---------------------------------------------------------------------------
__global__ __launch_bounds__(256, 2)
void k1_conv_gemm(const float* __restrict__ x, const float* __restrict__ w,
                  const float* __restrict__ bias, unsigned short* __restrict__ c) {
    __shared__ uint4 a_lds[8 * 129];  // A: 128 rows (b), pad->129
    __shared__ uint4 b_lds[8 * 113];  // B: 112 rows (o), pad->113
    const int tid  = threadIdx.x;
    const int n0   = blockIdx.x * 112;
    const int wave = tid >> 6, lane = tid & 63;
    const int quad = lane >> 4, m16 = lane & 15;

    f32x4 acc[2][7];
#pragma unroll
    for (int i = 0; i < 2; ++i)
#pragma unroll
        for (int j = 0; j < 7; ++j) acc[i][j] = (f32x4){0.f, 0.f, 0.f, 0.f};

    for (int kb = 0; kb < 1344; kb += 64) {
        // stage A: 1024 packets (128 rows x 8 kslots)
#pragma unroll
        for (int i = 0; i < 4; ++i) {
            int idx = tid + i * 256;
            int row = idx >> 3, ks = idx & 7;
            const float* gp = x + row * 1344 + kb + ks * 8;
            float4 f0 = *reinterpret_cast<const float4*>(gp);
            float4 f1 = *reinterpret_cast<const float4*>(gp + 4);
            a_lds[ks * 129 + row] = pack8(f0, f1);
        }
        // stage B: 896 packets (112 rows x 8 kslots)
#pragma unroll
        for (int i = 0; i < 4; ++i) {
            int idx = tid + i * 256;
            if (idx < 896) {
                int row = idx >> 3, ks = idx & 7;
                const float* gp = w + (size_t)(n0 + row) * 1344 + kb + ks * 8;
                float4 f0 = *reinterpret_cast<const float4*>(gp);
                float4 f1 = *reinterpret_cast<const float4*>(gp + 4);
                b_lds[ks * 113 + row] = pack8(f0, f1);
            }
        }
        __syncthreads();
#pragma unroll
        for (int half = 0; half < 2; ++half) {
            const int kp = half * 4 + quad;  // k-packet index for this lane
            short8 af[2], bfr[7];
#pragma unroll
            for (int rt = 0; rt < 2; ++rt)
                af[rt] = ((const short8*)a_lds)[kp * 129 + wave * 32 + rt * 16 + m16];
#pragma unroll
            for (int ct = 0; ct < 7; ++ct)
                bfr[ct] = ((const short8*)b_lds)[kp * 113 + ct * 16 + m16];
#pragma unroll
            for (int rt = 0; rt < 2; ++rt)
#pragma unroll
                for (int ct = 0; ct < 7; ++ct)
                    acc[rt][ct] = __builtin_amdgcn_mfma_f32_16x16x32_bf16(
                        af[rt], bfr[ct], acc[rt][ct], 0, 0, 0);
        }
        __syncthreads();
    }
    // epilogue: bias + relu + bf16 store. D map: row=(lane>>4)*4+r, col=lane&15
#pragma unroll
    for (int ct = 0; ct < 7; ++ct) {
        int col = n0 + ct * 16 + m16;
        float bv = bias[col];
#pragma unroll
        for (int rt = 0; rt < 2; ++rt) {
#pragma unroll
            for (int r = 0; r < 4; ++r) {
                int grow = wave * 32 + rt * 16 + quad * 4 + r;  // b
                float v = acc[rt][ct][r] + bv;
                v = fmaxf(v, 0.f);
                c[(size_t)grow * 50400 + col] = bf16rn(v);
            }
        }
    }
}

// ---------------------------------------------------------------------------
// K2: res1_tbh[t][b][hc] = sum_{k<6} c[b][hc*1008 + 169k + t], t in [0,163)
// One block per b; LDS-transposed so reads and writes both coalesce.
// ---------------------------------------------------------------------------
__global__ __launch_bounds__(256)
void k2_diag(const unsigned short* __restrict__ c, float* __restrict__ res1) {
    __shared__ float rloc[50 * 164];  // [hc][t], t padded 163->164
    const int b = blockIdx.x;
    const unsigned short* cb = c + (size_t)b * 50400;
    for (int idx = threadIdx.x; idx < 8150; idx += 256) {
        int hc = idx / 163, t = idx - hc * 163;
        int base = hc * 1008 + t;
        float s = 0.f;
#pragma unroll
        for (int k = 0; k < 6; ++k) s += bf2f(cb[base + 169 * k]);
        rloc[hc * 164 + t] = s;
    }
    __syncthreads();
    for (int idx = threadIdx.x; idx < 8150; idx += 256) {
        int t = idx / 50, hc = idx - t * 50;
        res1[(size_t)(t * 128 + b) * 50 + hc] = rloc[hc * 164 + t];
    }
}

// ---------------------------------------------------------------------------
// K3a: gi1[(t*128+b)][150] = res1_row(50) @ g1_wih^T + g1_bih  (20864 rows)
// ---------------------------------------------------------------------------
__global__ __launch_bounds__(256)
void k3_gi1(const float* __restrict__ res1, const float* __restrict__ wih,
            const float* __restrict__ bih, float* __restrict__ gi1) {
    __shared__ float wl[150 * 51];  // padded rows -> 2-way max on reads
    __shared__ float xl[32 * 50];
    const int row0 = blockIdx.x * 32;
    for (int idx = threadIdx.x; idx < 7500; idx += 256) {
        int r = idx / 50, j = idx - r * 50;
        wl[r * 51 + j] = wih[idx];
    }
    for (int idx = threadIdx.x; idx < 1600; idx += 256)
        xl[idx] = res1[(size_t)row0 * 50 + idx];
    __syncthreads();
    for (int e = threadIdx.x; e < 4800; e += 256) {
        int rr = e / 150, cc = e - rr * 150;
        float acc = bih[cc];
        const float* xp = &xl[rr * 50];
        const float* wp = &wl[cc * 51];
#pragma unroll
        for (int j = 0; j < 50; ++j) acc += xp[j] * wp[j];
        gi1[(size_t)(row0 + rr) * 150 + cc] = acc;
    }
}

// ---------------------------------------------------------------------------
// K3b: gi2[(pt*3072+bsk)][15] from res1_tbh rows t = 19 + pt*24 + sk (18432 rows)
// ---------------------------------------------------------------------------
__global__ __launch_bounds__(256)
void k3_gi2(const float* __restrict__ res1, const float* __restrict__ wih,
            const float* __restrict__ bih, float* __restrict__ gi2) {
    __shared__ float wl[15 * 51];
    __shared__ float xl[32 * 50];
    const int row0 = blockIdx.x * 32;
    for (int idx = threadIdx.x; idx < 750; idx += 256) {
        int r = idx / 50, j = idx - r * 50;
        wl[r * 51 + j] = wih[idx];
    }
    for (int idx = threadIdx.x; idx < 1600; idx += 256) {
        int rr = idx / 50, j = idx - rr * 50;
        int r = row0 + rr;
        int pt = r / 3072, bsk = r - pt * 3072;
        int b = bsk / 24, sk = bsk - b * 24;
        int t = 19 + pt * 24 + sk;
        xl[idx] = res1[(size_t)(t * 128 + b) * 50 + j];
    }
    __syncthreads();
    for (int e = threadIdx.x; e < 480; e += 256) {
        int rr = e / 15, cc = e - rr * 15;
        float acc = bih[cc];
#pragma unroll
        for (int j = 0; j < 50; ++j) acc += xl[rr * 50 + j] * wl[cc * 51 + j];
        gi2[(size_t)(row0 + rr) * 15 + cc] = acc;
    }
}

// ---------------------------------------------------------------------------
// K4: GRU1 recurrence. One wave per batch element (128 blocks x 64 threads).
// Lane l<50 owns hidden unit l: w_hh rows l, 50+l, 100+l live in VGPRs.
// h broadcast via LDS float4 reads; 163 sequential steps.
// ---------------------------------------------------------------------------
__global__ __launch_bounds__(64)
void k4_gru1(const float* __restrict__ gi1, const float* __restrict__ whh,
             const float* __restrict__ bhh, float* __restrict__ r1) {
    __shared__ float wl[7500];
    __shared__ __align__(16) float hl[52];
    const int b = blockIdx.x;
    const int l = threadIdx.x;
    for (int idx = l; idx < 7500; idx += 64) wl[idx] = whh[idx];
    if (l < 52) hl[l] = 0.f;
    __syncthreads();
    const int lc = (l < 50) ? l : 49;
    float wr[50], wz[50], wn[50];
#pragma unroll
    for (int j = 0; j < 50; ++j) {
        wr[j] = wl[lc * 50 + j];
        wz[j] = wl[(50 + lc) * 50 + j];
        wn[j] = wl[(100 + lc) * 50 + j];
    }
    const float bhr = bhh[lc], bhz = bhh[50 + lc], bhn = bhh[100 + lc];
    float hcur = 0.f;
    for (int t = 0; t < 163; ++t) {
        const float* gp = gi1 + ((size_t)t * 128 + b) * 150;
        float gir = gp[lc], giz = gp[50 + lc], gin = gp[100 + lc];
        float ar = bhr, az = bhz, an = bhn;
#pragma unroll
        for (int j4 = 0; j4 < 12; ++j4) {
            float4 hv = *reinterpret_cast<const float4*>(&hl[4 * j4]);
            ar += wr[4 * j4 + 0] * hv.x + wr[4 * j4 + 1] * hv.y +
                  wr[4 * j4 + 2] * hv.z + wr[4 * j4 + 3] * hv.w;
            az += wz[4 * j4 + 0] * hv.x + wz[4 * j4 + 1] * hv.y +
                  wz[4 * j4 + 2] * hv.z + wz[4 * j4 + 3] * hv.w;
            an += wn[4 * j4 + 0] * hv.x + wn[4 * j4 + 1] * hv.y +
                  wn[4 * j4 + 2] * hv.z + wn[4 * j4 + 3] * hv.w;
        }
        {
            float h48 = hl[48], h49 = hl[49];
            ar += wr[48] * h48 + wr[49] * h49;
            az += wz[48] * h48 + wz[49] * h49;
            an += wn[48] * h48 + wn[49] * h49;
        }
        float rg = sigmf(gir + ar);
        float zg = sigmf(giz + az);
        float ng = tanhf_(gin + rg * an);
        float hn = (1.f - zg) * ng + zg * hcur;
        __syncthreads();                // all lanes done reading old h
        if (l < 50) { hl[l] = hn; hcur = hn; }
        __syncthreads();                // new h visible
    }
    if (l < 50) r1[b * 50 + l] = hcur;
}

// ---------------------------------------------------------------------------
// K5: GRU2 recurrence. 3072 independent sequences, one thread each, 6 steps.
// ---------------------------------------------------------------------------
__global__ __launch_bounds__(256)
void k5_gru2(const float* __restrict__ gi2, const float* __restrict__ whh,
             const float* __restrict__ bhh, float* __restrict__ hs) {
    __shared__ float wl[75];
    __shared__ float bl[15];
    const int tid = threadIdx.x;
    if (tid < 75) wl[tid] = whh[tid];
    if (tid < 15) bl[tid] = bhh[tid];
    __syncthreads();
    const int bsk = blockIdx.x * 256 + tid;
    float h[5] = {0.f, 0.f, 0.f, 0.f, 0.f};
    for (int pt = 0; pt < 6; ++pt) {
        const float* gp = gi2 + (size_t)(pt * 3072 + bsk) * 15;
        float gi[15];
#pragma unroll
        for (int i = 0; i < 15; ++i) gi[i] = gp[i];
        float gh[15];
#pragma unroll
        for (int i = 0; i < 15; ++i) {
            float s = bl[i];
#pragma unroll
            for (int j = 0; j < 5; ++j) s += wl[i * 5 + j] * h[j];
            gh[i] = s;
        }
#pragma unroll
        for (int u = 0; u < 5; ++u) {
            float rg = sigmf(gi[u] + gh[u]);
            float zg = sigmf(gi[5 + u] + gh[5 + u]);
            float ng = tanhf_(gi[10 + u] + rg * gh[10 + u]);
            h[u] = (1.f - zg) * ng + zg * h[u];
        }
    }
#pragma unroll
    for (int u = 0; u < 5; ++u) hs[bsk * 5 + u] = h[u];
}

// ---------------------------------------------------------------------------
// K6: out[b][m] = sigmoid(r_cat @ l1_w^T + l1_b + highway(x))
// ---------------------------------------------------------------------------
__global__ __launch_bounds__(256)
void k6_final(const float* __restrict__ r1, const float* __restrict__ hs,
              const float* __restrict__ l1w, const float* __restrict__ l1b,
              const float* __restrict__ x, const float* __restrict__ hww,
              const float* __restrict__ hwb, float* __restrict__ out) {
    const int tid = blockIdx.x * 256 + threadIdx.x;
    if (tid >= 1024) return;
    const int b = tid >> 3, m = tid & 7;
    float acc = l1b[m];
    const float* wrow = l1w + m * 170;
    const float* rb = r1 + b * 50;
#pragma unroll
    for (int j = 0; j < 50; ++j) acc += rb[j] * wrow[j];
    const float* hb = hs + b * 120;
#pragma unroll
    for (int j = 0; j < 120; ++j) acc += hb[j] * wrow[50 + j];
    float z = hwb[0];
    const float* xb = x + b * 1344 + 144 * 8 + m;
#pragma unroll
    for (int wi = 0; wi < 24; ++wi) z += xb[wi * 8] * hww[wi];
    out[tid] = 1.f / (1.f + __expf(-(acc + z)));
}

// ---------------------------------------------------------------------------
extern "C" void kernel_launch(void* const* d_in, const int* in_sizes, int n_in,
                              void* d_out, int out_size, void* d_ws, size_t ws_size,
                              hipStream_t stream) {
    const float* x      = (const float*)d_in[0];
    const float* conv_w = (const float*)d_in[1];
    const float* conv_b = (const float*)d_in[2];
    const float* g1_wih = (const float*)d_in[3];
    const float* g1_whh = (const float*)d_in[4];
    const float* g1_bih = (const float*)d_in[5];
    const float* g1_bhh = (const float*)d_in[6];
    const float* gs_wih = (const float*)d_in[7];
    const float* gs_whh = (const float*)d_in[8];
    const float* gs_bih = (const float*)d_in[9];
    const float* gs_bhh = (const float*)d_in[10];
    const float* l1_w   = (const float*)d_in[11];
    const float* l1_b   = (const float*)d_in[12];
    const float* hw_w   = (const float*)d_in[13];
    const float* hw_b   = (const float*)d_in[14];
    float* out = (float*)d_out;

    char* ws = (char*)d_ws;
    // ws layout (29.4 MB total)
    unsigned short* c   = (unsigned short*)(ws);               // 12,902,400 B
    float* res1         = (float*)(ws + 12902400);             //  4,172,800 B
    float* gi1          = (float*)(ws + 17075200);             // 12,518,400 B
    float* gi2          = (float*)(ws + 29593600);             //  1,105,920 B
    float* r1           = (float*)(ws + 30699520);             //     25,600 B
    float* hs           = (float*)(ws + 30725120);             //     61,440 B

    hipLaunchKernelGGL(k1_conv_gemm, dim3(450), dim3(256), 0, stream, x, conv_w, conv_b, c);
    hipLaunchKernelGGL(k2_diag,      dim3(128), dim3(256), 0, stream, c, res1);
    hipLaunchKernelGGL(k3_gi1,       dim3(652), dim3(256), 0, stream, res1, g1_wih, g1_bih, gi1);
    hipLaunchKernelGGL(k3_gi2,       dim3(576), dim3(256), 0, stream, res1, gs_wih, gs_bih, gi2);
    hipLaunchKernelGGL(k4_gru1,      dim3(128), dim3(64),  0, stream, gi1, g1_whh, g1_bhh, r1);
    hipLaunchKernelGGL(k5_gru2,      dim3(12),  dim3(256), 0, stream, gi2, gs_whh, gs_bhh, hs);
    hipLaunchKernelGGL(k6_final,     dim3(4),   dim3(256), 0, stream, r1, hs, l1_w, l1_b, x, hw_w, hw_b, out);
}

// Round 2
// 588.089 us; speedup vs baseline: 1.0508x; 1.0508x over previous
//
#include <hip/hip_runtime.h>
#include <hip/hip_bf16.h>
#include <cstdint>

// Problem constants
// B=128, P=168, M=8, HIDC=50, HIDR=50, HIDS=5, CK=6, SKIP=24, HW=24
// O = P*HIDC*CK = 50400, Kdim = P*M = 1344, L = 163, PT = 6

typedef __attribute__((ext_vector_type(8))) short short8;   // 8 bf16 (4 VGPRs)
typedef __attribute__((ext_vector_type(4))) float f32x4;    // MFMA acc

__device__ __forceinline__ unsigned short bf16rn(float f) {
    unsigned u = __float_as_uint(f);
    return (unsigned short)((u + 0x7FFFu + ((u >> 16) & 1u)) >> 16);
}
__device__ __forceinline__ unsigned pk2(float a, float b) {
    return ((unsigned)bf16rn(b) << 16) | (unsigned)bf16rn(a);
}
__device__ __forceinline__ uint4 pack8(float4 f0, float4 f1) {
    uint4 u;
    u.x = pk2(f0.x, f0.y); u.y = pk2(f0.z, f0.w);
    u.z = pk2(f1.x, f1.y); u.w = pk2(f1.z, f1.w);
    return u;
}
__device__ __forceinline__ float bf2f(unsigned short u) {
    return __uint_as_float((unsigned)u << 16);
}
__device__ __forceinline__ float sigmf(float x) { return 1.f / (1.f + __expf(-x)); }
__device__ __forceinline__ float tanhf_(float x) { return 1.f - 2.f / (__expf(2.f * x) + 1.f); }

// ---------------------------------------------------------------------------
// K1: c[b][o] = relu(xf @ wf^T + conv_b), stored bf16.  M=128, N=50400, K=1344.
// Tile 128x112, BK=64. Software-pipelined: global fp32 loads for tile k+1 are
// issued right after the first barrier and consumed (bf16-pack -> LDS) at the
// top of the next iteration, so HBM latency overlaps the MFMA of tile k.
// ---------------------------------------------------------------------------
__global__ __launch_bounds__(256, 2)
void k1_conv_gemm(const float* __restrict__ x, const float* __restrict__ w,
                  const float* __restrict__ bias, unsigned short* __restrict__ c) {
    __shared__ uint4 a_lds[8 * 129];  // A: 128 rows (b), pad->129
    __shared__ uint4 b_lds[8 * 113];  // B: 112 rows (o), pad->113
    const int tid  = threadIdx.x;
    const int n0   = blockIdx.x * 112;
    const int wave = tid >> 6, lane = tid & 63;
    const int quad = lane >> 4, m16 = lane & 15;

    f32x4 acc[2][7];
#pragma unroll
    for (int i = 0; i < 2; ++i)
#pragma unroll
        for (int j = 0; j < 7; ++j) acc[i][j] = (f32x4){0.f, 0.f, 0.f, 0.f};

    float4 pa[4][2];  // A prefetch regs
    float4 pb[4][2];  // B prefetch regs

    // issue global loads for K-slice starting at kb
    auto issue = [&](int kb) {
#pragma unroll
        for (int i = 0; i < 4; ++i) {
            int row = (tid >> 3) + 32 * i;
            const float* gp = x + row * 1344 + kb + (tid & 7) * 8;
            pa[i][0] = *reinterpret_cast<const float4*>(gp);
            pa[i][1] = *reinterpret_cast<const float4*>(gp + 4);
        }
#pragma unroll
        for (int i = 0; i < 4; ++i) {
            int idx = tid + 256 * i;
            if (idx < 896) {  // wave-uniform predicate (only waves 2,3 skip i=3)
                int row = idx >> 3;
                const float* gp = w + (size_t)(n0 + row) * 1344 + kb + (idx & 7) * 8;
                pb[i][0] = *reinterpret_cast<const float4*>(gp);
                pb[i][1] = *reinterpret_cast<const float4*>(gp + 4);
            }
        }
    };

    issue(0);
    for (int kb = 0; kb < 1344; kb += 64) {
        // commit prefetched regs -> bf16 LDS packets (vmcnt wait lands here)
#pragma unroll
        for (int i = 0; i < 4; ++i) {
            int idx = tid + 256 * i;
            int row = idx >> 3, ks = idx & 7;
            a_lds[ks * 129 + row] = pack8(pa[i][0], pa[i][1]);
        }
#pragma unroll
        for (int i = 0; i < 4; ++i) {
            int idx = tid + 256 * i;
            if (idx < 896) {
                int row = idx >> 3, ks = idx & 7;
                b_lds[ks * 113 + row] = pack8(pb[i][0], pb[i][1]);
            }
        }
        __syncthreads();
        if (kb + 64 < 1344) issue(kb + 64);  // overlap with MFMA below
#pragma unroll
        for (int half = 0; half < 2; ++half) {
            const int kp = half * 4 + quad;  // k-packet index for this lane
            short8 af[2], bfr[7];
#pragma unroll
            for (int rt = 0; rt < 2; ++rt)
                af[rt] = ((const short8*)a_lds)[kp * 129 + wave * 32 + rt * 16 + m16];
#pragma unroll
            for (int ct = 0; ct < 7; ++ct)
                bfr[ct] = ((const short8*)b_lds)[kp * 113 + ct * 16 + m16];
#pragma unroll
            for (int rt = 0; rt < 2; ++rt)
#pragma unroll
                for (int ct = 0; ct < 7; ++ct)
                    acc[rt][ct] = __builtin_amdgcn_mfma_f32_16x16x32_bf16(
                        af[rt], bfr[ct], acc[rt][ct], 0, 0, 0);
        }
        __syncthreads();
    }
    // epilogue: bias + relu + bf16 store. D map: row=(lane>>4)*4+r, col=lane&15
#pragma unroll
    for (int ct = 0; ct < 7; ++ct) {
        int col = n0 + ct * 16 + m16;
        float bv = bias[col];
#pragma unroll
        for (int rt = 0; rt < 2; ++rt) {
#pragma unroll
            for (int r = 0; r < 4; ++r) {
                int grow = wave * 32 + rt * 16 + quad * 4 + r;  // b
                float v = acc[rt][ct][r] + bv;
                v = fmaxf(v, 0.f);
                c[(size_t)grow * 50400 + col] = bf16rn(v);
            }
        }
    }
}

// ---------------------------------------------------------------------------
// K2: res1_tbh[t][b][hc] = sum_{k<6} c[b][hc*1008 + 169k + t], t in [0,163)
// One block per b; LDS-transposed so reads and writes both coalesce.
// ---------------------------------------------------------------------------
__global__ __launch_bounds__(256)
void k2_diag(const unsigned short* __restrict__ c, float* __restrict__ res1) {
    __shared__ float rloc[50 * 164];  // [hc][t], t padded 163->164
    const int b = blockIdx.x;
    const unsigned short* cb = c + (size_t)b * 50400;
    for (int idx = threadIdx.x; idx < 8150; idx += 256) {
        int hc = idx / 163, t = idx - hc * 163;
        int base = hc * 1008 + t;
        float s = 0.f;
#pragma unroll
        for (int k = 0; k < 6; ++k) s += bf2f(cb[base + 169 * k]);
        rloc[hc * 164 + t] = s;
    }
    __syncthreads();
    for (int idx = threadIdx.x; idx < 8150; idx += 256) {
        int t = idx / 50, hc = idx - t * 50;
        res1[(size_t)(t * 128 + b) * 50 + hc] = rloc[hc * 164 + t];
    }
}

// ---------------------------------------------------------------------------
// K3a: gi1[(t*128+b)][150] = res1_row(50) @ g1_wih^T + g1_bih  (20864 rows)
// 64 rows/block; LDS rows padded to 52 floats (208 B, 16B-aligned) -> float4 dots
// ---------------------------------------------------------------------------
__global__ __launch_bounds__(256)
void k3_gi1(const float* __restrict__ res1, const float* __restrict__ wih,
            const float* __restrict__ bih, float* __restrict__ gi1) {
    __shared__ float wl[150 * 52];
    __shared__ float xl[64 * 52];
    const int row0 = blockIdx.x * 64;
    for (int idx = threadIdx.x; idx < 7500; idx += 256) {
        int r = idx / 50, j = idx - r * 50;
        wl[r * 52 + j] = wih[idx];
    }
    for (int idx = threadIdx.x; idx < 3200; idx += 256) {
        int r = idx / 50, j = idx - r * 50;
        xl[r * 52 + j] = res1[(size_t)row0 * 50 + idx];
    }
    __syncthreads();
    for (int e = threadIdx.x; e < 9600; e += 256) {
        int rr = e / 150, cc = e - rr * 150;
        float4 a0 = {0.f, 0.f, 0.f, 0.f};
        const float* xp = &xl[rr * 52];
        const float* wp = &wl[cc * 52];
#pragma unroll
        for (int j = 0; j < 48; j += 4) {
            float4 xv = *reinterpret_cast<const float4*>(xp + j);
            float4 wv = *reinterpret_cast<const float4*>(wp + j);
            a0.x += xv.x * wv.x; a0.y += xv.y * wv.y;
            a0.z += xv.z * wv.z; a0.w += xv.w * wv.w;
        }
        float acc = bih[cc] + xp[48] * wp[48] + xp[49] * wp[49]
                  + (a0.x + a0.y) + (a0.z + a0.w);
        gi1[(size_t)(row0 + rr) * 150 + cc] = acc;
    }
}

// ---------------------------------------------------------------------------
// K3b: gi2[(pt*3072+bsk)][15] from res1_tbh rows t = 19 + pt*24 + sk (18432 rows)
// ---------------------------------------------------------------------------
__global__ __launch_bounds__(256)
void k3_gi2(const float* __restrict__ res1, const float* __restrict__ wih,
            const float* __restrict__ bih, float* __restrict__ gi2) {
    __shared__ float wl[15 * 52];
    __shared__ float xl[64 * 52];
    const int row0 = blockIdx.x * 64;
    for (int idx = threadIdx.x; idx < 750; idx += 256) {
        int r = idx / 50, j = idx - r * 50;
        wl[r * 52 + j] = wih[idx];
    }
    for (int idx = threadIdx.x; idx < 3200; idx += 256) {
        int rr = idx / 50, j = idx - rr * 50;
        int r = row0 + rr;
        int pt = r / 3072, bsk = r - pt * 3072;
        int b = bsk / 24, sk = bsk - b * 24;
        int t = 19 + pt * 24 + sk;
        xl[rr * 52 + j] = res1[(size_t)(t * 128 + b) * 50 + j];
    }
    __syncthreads();
    for (int e = threadIdx.x; e < 960; e += 256) {
        int rr = e / 15, cc = e - rr * 15;
        float4 a0 = {0.f, 0.f, 0.f, 0.f};
        const float* xp = &xl[rr * 52];
        const float* wp = &wl[cc * 52];
#pragma unroll
        for (int j = 0; j < 48; j += 4) {
            float4 xv = *reinterpret_cast<const float4*>(xp + j);
            float4 wv = *reinterpret_cast<const float4*>(wp + j);
            a0.x += xv.x * wv.x; a0.y += xv.y * wv.y;
            a0.z += xv.z * wv.z; a0.w += xv.w * wv.w;
        }
        float acc = bih[cc] + xp[48] * wp[48] + xp[49] * wp[49]
                  + (a0.x + a0.y) + (a0.z + a0.w);
        gi2[(size_t)(row0 + rr) * 15 + cc] = acc;
    }
}

// ---------------------------------------------------------------------------
// K4: GRU1 recurrence. One wave per batch element (128 blocks x 64 threads).
// Lane l<50 owns hidden unit l: w_hh rows l, 50+l, 100+l live in VGPRs.
// Double-buffered h in LDS -> ONE barrier per step; next-step gi prefetched
// into regs before the barrier so global latency never sits on the chain.
// ---------------------------------------------------------------------------
__global__ __launch_bounds__(64)
void k4_gru1(const float* __restrict__ gi1, const float* __restrict__ whh,
             const float* __restrict__ bhh, float* __restrict__ r1) {
    __shared__ float wl[7500];
    __shared__ __align__(16) float hl[2][64];
    const int b = blockIdx.x;
    const int l = threadIdx.x;
    for (int idx = l; idx < 7500; idx += 64) wl[idx] = whh[idx];
    hl[0][l] = 0.f;
    hl[1][l] = 0.f;
    __syncthreads();
    const int lc = (l < 50) ? l : 49;
    float wr[50], wz[50], wn[50];
#pragma unroll
    for (int j = 0; j < 50; ++j) {
        wr[j] = wl[lc * 50 + j];
        wz[j] = wl[(50 + lc) * 50 + j];
        wn[j] = wl[(100 + lc) * 50 + j];
    }
    const float bhr = bhh[lc], bhz = bhh[50 + lc], bhn = bhh[100 + lc];
    float hcur = 0.f;
    const float* gp = gi1 + (size_t)b * 150;   // t-stride = 128*150
    float gir = gp[lc], giz = gp[50 + lc], gin = gp[100 + lc];
    int p = 0;
    for (int t = 0; t < 163; ++t) {
        // prefetch next step's input projection early
        float ngir = 0.f, ngiz = 0.f, ngin = 0.f;
        if (t < 162) {
            const float* gq = gp + 150 * 128;
            ngir = gq[lc]; ngiz = gq[50 + lc]; ngin = gq[100 + lc];
        }
        const float* hp = hl[p];
        float ar = bhr, az = bhz, an = bhn;
#pragma unroll
        for (int j4 = 0; j4 < 12; ++j4) {
            float4 hv = *reinterpret_cast<const float4*>(hp + 4 * j4);
            ar += wr[4 * j4 + 0] * hv.x + wr[4 * j4 + 1] * hv.y +
                  wr[4 * j4 + 2] * hv.z + wr[4 * j4 + 3] * hv.w;
            az += wz[4 * j4 + 0] * hv.x + wz[4 * j4 + 1] * hv.y +
                  wz[4 * j4 + 2] * hv.z + wz[4 * j4 + 3] * hv.w;
            an += wn[4 * j4 + 0] * hv.x + wn[4 * j4 + 1] * hv.y +
                  wn[4 * j4 + 2] * hv.z + wn[4 * j4 + 3] * hv.w;
        }
        {
            float h48 = hp[48], h49 = hp[49];
            ar += wr[48] * h48 + wr[49] * h49;
            az += wz[48] * h48 + wz[49] * h49;
            an += wn[48] * h48 + wn[49] * h49;
        }
        float rg = sigmf(gir + ar);
        float zg = sigmf(giz + az);
        float ng = tanhf_(gin + rg * an);
        float hn = (1.f - zg) * ng + zg * hcur;
        hl[1 - p][l] = hn;              // write other buffer (no WAR on readers)
        __syncthreads();                // writes visible; one barrier per step
        p ^= 1;
        hcur = hn;
        gir = ngir; giz = ngiz; gin = ngin;
        gp += 150 * 128;
    }
    if (l < 50) r1[b * 50 + l] = hcur;
}

// ---------------------------------------------------------------------------
// K5: GRU2 recurrence. 3072 independent sequences, one thread each, 6 steps.
// ---------------------------------------------------------------------------
__global__ __launch_bounds__(256)
void k5_gru2(const float* __restrict__ gi2, const float* __restrict__ whh,
             const float* __restrict__ bhh, float* __restrict__ hs) {
    __shared__ float wl[75];
    __shared__ float bl[15];
    const int tid = threadIdx.x;
    if (tid < 75) wl[tid] = whh[tid];
    if (tid < 15) bl[tid] = bhh[tid];
    __syncthreads();
    const int bsk = blockIdx.x * 256 + tid;
    float h[5] = {0.f, 0.f, 0.f, 0.f, 0.f};
    for (int pt = 0; pt < 6; ++pt) {
        const float* gp = gi2 + (size_t)(pt * 3072 + bsk) * 15;
        float gi[15];
#pragma unroll
        for (int i = 0; i < 15; ++i) gi[i] = gp[i];
        float gh[15];
#pragma unroll
        for (int i = 0; i < 15; ++i) {
            float s = bl[i];
#pragma unroll
            for (int j = 0; j < 5; ++j) s += wl[i * 5 + j] * h[j];
            gh[i] = s;
        }
#pragma unroll
        for (int u = 0; u < 5; ++u) {
            float rg = sigmf(gi[u] + gh[u]);
            float zg = sigmf(gi[5 + u] + gh[5 + u]);
            float ng = tanhf_(gi[10 + u] + rg * gh[10 + u]);
            h[u] = (1.f - zg) * ng + zg * h[u];
        }
    }
#pragma unroll
    for (int u = 0; u < 5; ++u) hs[bsk * 5 + u] = h[u];
}

// ---------------------------------------------------------------------------
// K6: out[b][m] = sigmoid(r_cat @ l1_w^T + l1_b + highway(x))
// ---------------------------------------------------------------------------
__global__ __launch_bounds__(256)
void k6_final(const float* __restrict__ r1, const float* __restrict__ hs,
              const float* __restrict__ l1w, const float* __restrict__ l1b,
              const float* __restrict__ x, const float* __restrict__ hww,
              const float* __restrict__ hwb, float* __restrict__ out) {
    const int tid = blockIdx.x * 256 + threadIdx.x;
    if (tid >= 1024) return;
    const int b = tid >> 3, m = tid & 7;
    float acc = l1b[m];
    const float* wrow = l1w + m * 170;
    const float* rb = r1 + b * 50;
#pragma unroll
    for (int j = 0; j < 50; ++j) acc += rb[j] * wrow[j];
    const float* hb = hs + b * 120;
#pragma unroll
    for (int j = 0; j < 120; ++j) acc += hb[j] * wrow[50 + j];
    float z = hwb[0];
    const float* xb = x + b * 1344 + 144 * 8 + m;
#pragma unroll
    for (int wi = 0; wi < 24; ++wi) z += xb[wi * 8] * hww[wi];
    out[tid] = 1.f / (1.f + __expf(-(acc + z)));
}

// ---------------------------------------------------------------------------
extern "C" void kernel_launch(void* const* d_in, const int* in_sizes, int n_in,
                              void* d_out, int out_size, void* d_ws, size_t ws_size,
                              hipStream_t stream) {
    const float* x      = (const float*)d_in[0];
    const float* conv_w = (const float*)d_in[1];
    const float* conv_b = (const float*)d_in[2];
    const float* g1_wih = (const float*)d_in[3];
    const float* g1_whh = (const float*)d_in[4];
    const float* g1_bih = (const float*)d_in[5];
    const float* g1_bhh = (const float*)d_in[6];
    const float* gs_wih = (const float*)d_in[7];
    const float* gs_whh = (const float*)d_in[8];
    const float* gs_bih = (const float*)d_in[9];
    const float* gs_bhh = (const float*)d_in[10];
    const float* l1_w   = (const float*)d_in[11];
    const float* l1_b   = (const float*)d_in[12];
    const float* hw_w   = (const float*)d_in[13];
    const float* hw_b   = (const float*)d_in[14];
    float* out = (float*)d_out;

    char* ws = (char*)d_ws;
    // ws layout (~30.8 MB total)
    unsigned short* c   = (unsigned short*)(ws);               // 12,902,400 B
    float* res1         = (float*)(ws + 12902400);             //  4,172,800 B
    float* gi1          = (float*)(ws + 17075200);             // 12,518,400 B
    float* gi2          = (float*)(ws + 29593600);             //  1,105,920 B
    float* r1           = (float*)(ws + 30699520);             //     25,600 B
    float* hs           = (float*)(ws + 30725120);             //     61,440 B

    hipLaunchKernelGGL(k1_conv_gemm, dim3(450), dim3(256), 0, stream, x, conv_w, conv_b, c);
    hipLaunchKernelGGL(k2_diag,      dim3(128), dim3(256), 0, stream, c, res1);
    hipLaunchKernelGGL(k3_gi1,       dim3(326), dim3(256), 0, stream, res1, g1_wih, g1_bih, gi1);
    hipLaunchKernelGGL(k3_gi2,       dim3(288), dim3(256), 0, stream, res1, gs_wih, gs_bih, gi2);
    hipLaunchKernelGGL(k4_gru1,      dim3(128), dim3(64),  0, stream, gi1, g1_whh, g1_bhh, r1);
    hipLaunchKernelGGL(k5_gru2,      dim3(12),  dim3(256), 0, stream, gi2, gs_whh, gs_bhh, hs);
    hipLaunchKernelGGL(k6_final,     dim3(4),   dim3(256), 0, stream, r1, hs, l1_w, l1_b, x, hw_w, hw_b, out);
}